// Round 13
// baseline (58.842 us; speedup 1.0000x reference)
//
#include <hip/hip_runtime.h>
#include <hip/hip_bf16.h>
#include <stdint.h>

// Problem: B=1024, IN=20000, NG=64, GIN=512, H1=256, GS=128
// o = x[:,idx] @ (W1@W2) + (b1@W2 + b2)   -- linear-linear collapse
//
// ws layout: G bf16 [1024][32768] B-MAJOR @0 (64MiB), Wc bf16 [64][128][512]
// @64MiB (8MiB), bias2 f32 [64][128] @72MiB (32KB). ws >= 72MiB+32KB.
//
// R13: gather de-lockstepped. Row-serial through 2x40KB bf16 buffers with NO
// barrier at the gather0->stage1 transition (disjoint buffers; 16 waves
// de-sync -> intra-block VMEM/LDS overlap, zero extra VGPR liveness) and
// PARITY ANTI-PHASE (odd blocks run rows swapped) so co-resident block pairs
// are in opposite phases. wb fused; gemm = R12 (64x128, 1024 blocks).

typedef __attribute__((ext_vector_type(4))) float f32x4;
typedef __attribute__((ext_vector_type(8))) __bf16 bf16x8;
typedef __attribute__((ext_vector_type(8))) uint16_t u16x8;

__device__ __forceinline__ uint16_t f2bf(float f) {
    uint32_t u = __float_as_uint(f);
    u += 0x7FFFu + ((u >> 16) & 1u);   // RNE
    return (uint16_t)(u >> 16);
}

__device__ __forceinline__ uint64_t pack4bf(f32x4 v) {
    return (uint64_t)f2bf(v[0]) | ((uint64_t)f2bf(v[1]) << 16)
         | ((uint64_t)f2bf(v[2]) << 32) | ((uint64_t)f2bf(v[3]) << 48);
}

// stage one x-row (f32) into a bf16 LDS buffer; 5 chunks/thread, tail-clamped
__device__ __forceinline__ void stage_row(uint16_t* buf, const float* __restrict__ xrow,
                                          int t) {
    #pragma unroll
    for (int i = 0; i < 5; ++i) {
        int c = t + i * 1024;
        int cs = c < 5000 ? c : 4999;
        f32x4 v = *(const f32x4*)(xrow + (size_t)cs * 4);
        uint32_t lo, hi;
        asm("v_cvt_pk_bf16_f32 %0, %1, %2" : "=v"(lo) : "v"(v[0]), "v"(v[1]));
        asm("v_cvt_pk_bf16_f32 %0, %1, %2" : "=v"(hi) : "v"(v[2]), "v"(v[3]));
        uint2 p2; p2.x = lo; p2.y = hi;
        *(uint2*)&buf[c * 4] = p2;
    }
}

// gather one row from a bf16 buffer; 32 feats/thread as 4 x (8 feats -> uint4)
__device__ __forceinline__ void gather_row(const uint16_t* buf, const int* __restrict__ idx,
                                           int t, int b, uint32_t* __restrict__ G32) {
    const int4* idx4 = (const int4*)idx;
    uint32_t* row = G32 + (size_t)b * 16384;     // b-major, 64KB row
    #pragma unroll
    for (int it = 0; it < 4; ++it) {
        int j8 = t + it * 1024;                  // 8-feature chunk id [0,4096)
        int4 va = idx4[j8 * 2];
        int4 vb = idx4[j8 * 2 + 1];
        uint32_t f0 = buf[va.x], f1 = buf[va.y];
        uint32_t f2 = buf[va.z], f3 = buf[va.w];
        uint32_t f4 = buf[vb.x], f5 = buf[vb.y];
        uint32_t f6 = buf[vb.z], f7 = buf[vb.w];
        uint4 p;
        p.x = f0 | (f1 << 16);
        p.y = f2 | (f3 << 16);
        p.z = f4 | (f5 << 16);
        p.w = f6 | (f7 << 16);
        *(uint4*)&row[j8 * 4] = p;               // 16B contiguous
    }
}

// ---------------- K1: fat prep (832 blocks x 1024) ----------------
// blocks [0,256):   wprep -- Wc[g][n][k] = (W1[g]@W2[g])^T bf16
// blocks [256,320): bias
// blocks [320,832): gather -- rows 2*(bid-320), +1; anti-phase by parity
__global__ __launch_bounds__(1024, 8) void k_prep(const float* __restrict__ x,
                                                  const int* __restrict__ idx,
                                                  const float* __restrict__ W1,
                                                  const float* __restrict__ b1,
                                                  const float* __restrict__ W2,
                                                  const float* __restrict__ b2,
                                                  uint16_t* __restrict__ Wc,
                                                  float* __restrict__ bias2,
                                                  uint32_t* __restrict__ G32) {
    __shared__ __align__(16) uint8_t smem[81920];
    const int bid = blockIdx.x;
    const int t = threadIdx.x;

    if (bid < 256) {
        // ---- wprep: 16 waves as 4x4; wave tile 32(m=k of Wc^T) x 32(n); BK=32 ----
        uint16_t* As = (uint16_t*)smem;             // [128][40]
        uint16_t* Bs = As + 5120;                   // [32][132]
        const int g = bid >> 2, mt = bid & 3;
        const int wid = t >> 6, l = t & 63;
        const int wm = wid >> 2, wn = wid & 3;
        const int q = l >> 4, lm = l & 15;
        const float* W1g = W1 + ((size_t)g * 512 + (size_t)mt * 128) * 256;
        const float* W2g = W2 + (size_t)g * 256 * 128;
        f32x4 acc[2][2];
        #pragma unroll
        for (int mi = 0; mi < 2; ++mi)
            #pragma unroll
            for (int ni = 0; ni < 2; ++ni) {
                f32x4 z = {0.f, 0.f, 0.f, 0.f};
                acc[mi][ni] = z;
            }
        for (int kt = 0; kt < 8; ++kt) {
            __syncthreads();
            {   // A: 128 x 32 f32 -> bf16 (1024 f32x4, 1/thread)
                int m = t >> 3, c4 = t & 7;
                f32x4 v = *(const f32x4*)(W1g + (size_t)m * 256 + kt * 32 + c4 * 4);
                *(uint64_t*)&As[m * 40 + c4 * 4] = pack4bf(v);
            }
            {   // B: 32(h) x 128(n)
                int h = t >> 5, n4 = t & 31;
                f32x4 v = *(const f32x4*)(W2g + (size_t)(kt * 32 + h) * 128 + n4 * 4);
                *(uint64_t*)&Bs[h * 132 + n4 * 4] = pack4bf(v);
            }
            __syncthreads();
            bf16x8 a[2];
            #pragma unroll
            for (int mi = 0; mi < 2; ++mi)
                a[mi] = *(const bf16x8*)&As[(wm * 32 + mi * 16 + lm) * 40 + q * 8];
            #pragma unroll
            for (int ni = 0; ni < 2; ++ni) {
                int n = wn * 32 + ni * 16 + lm;
                u16x8 bu;
                #pragma unroll
                for (int j = 0; j < 8; ++j) bu[j] = Bs[(q * 8 + j) * 132 + n];
                bf16x8 bv = __builtin_bit_cast(bf16x8, bu);
                #pragma unroll
                for (int mi = 0; mi < 2; ++mi)
                    acc[mi][ni] = __builtin_amdgcn_mfma_f32_16x16x32_bf16(a[mi], bv, acc[mi][ni], 0, 0, 0);
            }
        }
        uint16_t* Wcg = Wc + (size_t)g * 128 * 512;
        #pragma unroll
        for (int mi = 0; mi < 2; ++mi) {
            int k0 = mt * 128 + wm * 32 + mi * 16 + q * 4;
            #pragma unroll
            for (int ni = 0; ni < 2; ++ni) {
                int n = wn * 32 + ni * 16 + lm;
                *(uint64_t*)&Wcg[(size_t)n * 512 + k0] = pack4bf(acc[mi][ni]);
            }
        }
    } else if (bid < 320) {
        // ---- bias2[g][n] = b1[g] @ W2[g,:,n] + b2[g][n] ----
        if (t < 128) {
            const int g = bid - 256, n = t;
            const float* w = W2 + (size_t)g * 256 * 128 + n;
            const float* bb = b1 + g * 256;
            float s = b2[g * 128 + n];
            for (int h = 0; h < 256; ++h) s += bb[h] * w[(size_t)h * 128];
            bias2[g * 128 + n] = s;
        }
    } else {
        // ---- gather: 2 rows serial, 2x40KB bf16 bufs, parity anti-phase ----
        uint16_t* buf0 = (uint16_t*)smem;            // [20480] bf16
        uint16_t* buf1 = buf0 + 20480;
        const int gb = bid - 320;
        const int par = gb & 1;
        const int rA = gb * 2 + par;                 // even: b0,b1; odd: b1,b0
        const int rB = gb * 2 + (par ^ 1);

        stage_row(buf0, x + (size_t)rA * 20000, t);
        __syncthreads();                             // buf0 ready
        gather_row(buf0, idx, t, rA, G32);
        // NO barrier: stage1 writes buf1 (disjoint); waves de-sync here ->
        // late waves still gather (LDS/store) while early waves load x (VMEM)
        stage_row(buf1, x + (size_t)rB * 20000, t);
        __syncthreads();                             // buf1 ready (all waves)
        gather_row(buf1, idx, t, rB, G32);
    }
}

// ---------------- K2: out[b, g*128+n] = G[b] @ Wc[g]^T + bias2[g] ----------------
// R12 gemm: 64x128 tile, 1024 blocks, 256 thr, 2x2 waves (32x64 each), 24KB
// LDS -> 4 blocks/CU. global_load_lds + XOR swizzle via pre-swizzled source.
__global__ __launch_bounds__(256) void k_gemm(const uint16_t* __restrict__ G,
                                              const uint16_t* __restrict__ Wc,
                                              const float* __restrict__ bias2,
                                              float* __restrict__ out) {
    __shared__ uint16_t sh[12288];               // A: [0,4096), B: [4096,12288)
    uint16_t* As = sh;                           // [64][64]
    uint16_t* Bs = sh + 4096;                    // [128][64]
    const int wg = (blockIdx.x & 7) * 128 + (blockIdx.x >> 3);   // XCD swizzle
    const int g = wg >> 4, mt = wg & 15;         // 64 g x 16 mtiles
    const int t = threadIdx.x;
    const int wid = t >> 6, l = t & 63;
    const int wm = wid >> 1, wn = wid & 1;       // 2x2 waves, 32(m) x 64(n)
    const int q = l >> 4, lm = l & 15;
    const int lrow = l >> 3;
    const int lcolsw = ((l & 7) ^ lrow) * 8;     // inverse-swizzled col (elems)
    const uint16_t* Ga = G + (size_t)mt * 64 * 32768 + (size_t)g * 512;  // b-major
    const uint16_t* Wa = Wc + (size_t)g * 65536;

    f32x4 acc[2][4];
    #pragma unroll
    for (int mi = 0; mi < 2; ++mi)
        #pragma unroll
        for (int ni = 0; ni < 4; ++ni) {
            f32x4 z = {0.f, 0.f, 0.f, 0.f};
            acc[mi][ni] = z;
        }

    for (int kt = 0; kt < 8; ++kt) {
        __syncthreads();
        #pragma unroll
        for (int i = 0; i < 2; ++i) {             // A: 64 rows
            const int rowbase = wid * 8 + i * 32;
            const uint16_t* sA = Ga + (size_t)(rowbase + lrow) * 32768 + kt * 64 + lcolsw;
            __builtin_amdgcn_global_load_lds(
                (const __attribute__((address_space(1))) void*)sA,
                (__attribute__((address_space(3))) void*)(As + rowbase * 64), 16, 0, 0);
        }
        #pragma unroll
        for (int i = 0; i < 4; ++i) {             // B: 128 rows
            const int rowbase = wid * 8 + i * 32;
            const uint16_t* sB = Wa + (size_t)(rowbase + lrow) * 512 + kt * 64 + lcolsw;
            __builtin_amdgcn_global_load_lds(
                (const __attribute__((address_space(1))) void*)sB,
                (__attribute__((address_space(3))) void*)(Bs + rowbase * 64), 16, 0, 0);
        }
        __syncthreads();
        #pragma unroll
        for (int kk = 0; kk < 2; ++kk) {
            bf16x8 a[2], b[4];
            #pragma unroll
            for (int mi = 0; mi < 2; ++mi) {
                int row = wm * 32 + mi * 16 + lm;
                int off = row * 64 + ((kk * 32 + q * 8) ^ ((lm & 7) * 8));
                a[mi] = *(const bf16x8*)&As[off];
            }
            #pragma unroll
            for (int ni = 0; ni < 4; ++ni) {
                int row = wn * 64 + ni * 16 + lm;
                int off = row * 64 + ((kk * 32 + q * 8) ^ ((lm & 7) * 8));
                b[ni] = *(const bf16x8*)&Bs[off];
            }
            #pragma unroll
            for (int mi = 0; mi < 2; ++mi)
                #pragma unroll
                for (int ni = 0; ni < 4; ++ni)
                    acc[mi][ni] = __builtin_amdgcn_mfma_f32_16x16x32_bf16(a[mi], b[ni], acc[mi][ni], 0, 0, 0);
        }
    }
    float bn[4];
    #pragma unroll
    for (int ni = 0; ni < 4; ++ni) bn[ni] = bias2[g * 128 + wn * 64 + ni * 16 + lm];
    #pragma unroll
    for (int mi = 0; mi < 2; ++mi)
        #pragma unroll
        for (int ni = 0; ni < 4; ++ni) {
            int col = g * 128 + wn * 64 + ni * 16 + lm;
            #pragma unroll
            for (int r = 0; r < 4; ++r) {
                int brow = mt * 64 + wm * 32 + mi * 16 + q * 4 + r;
                out[(size_t)brow * 8192 + col] = acc[mi][ni][r] + bn[ni];
            }
        }
}

extern "C" void kernel_launch(void* const* d_in, const int* in_sizes, int n_in,
                              void* d_out, int out_size, void* d_ws, size_t ws_size,
                              hipStream_t stream) {
    (void)in_sizes; (void)n_in; (void)out_size; (void)ws_size;
    const float* x   = (const float*)d_in[0];
    const int*   idx = (const int*)d_in[1];
    const float* W1  = (const float*)d_in[2];
    const float* b1  = (const float*)d_in[3];
    const float* W2  = (const float*)d_in[4];
    const float* b2  = (const float*)d_in[5];
    float* out = (float*)d_out;

    uint16_t* G     = (uint16_t*)d_ws;                                  // 64 MiB
    uint16_t* Wc    = (uint16_t*)((char*)d_ws + (size_t)(64 << 20));    //  8 MiB
    float*    bias2 = (float*)   ((char*)d_ws + (size_t)(72 << 20));    // 32 KiB

    k_prep<<<832, 1024, 0, stream>>>(x, idx, W1, b1, W2, b2, Wc, bias2, (uint32_t*)G);
    k_gemm<<<1024, 256, 0, stream>>>(G, Wc, bias2, out);
}